// Round 9
// baseline (244.825 us; speedup 1.0000x reference)
//
#include <hip/hip_runtime.h>

#define SEQ 2048
#define BSZ 2
#define NHEAD 16
#define NBH (BSZ * NHEAD)   // 32
#define HDIM 64
#define QBLK 64
#define KVBLK 64
#define NQT (SEQ / QBLK)    // 32
#define PSTR 72             // P tile LDS stride
#define ZSTR 72             // Zt LDS stride
#define ROWSTRIDE (BSZ * NHEAD * HDIM)

typedef __bf16 bf16x8 __attribute__((ext_vector_type(8)));
typedef float f32x4 __attribute__((ext_vector_type(4)));

__device__ __forceinline__ int zswz(int row, int col) {
  return row * ZSTR + (col ^ (((row >> 2) & 7) << 3));
}

// ---- pre-pass 1: K fp32 [s][b][h][d] -> bf16 [bh][s][d] ----
__global__ __launch_bounds__(256)
void conv_k(const float* __restrict__ Kg, __bf16* __restrict__ Kb) {
  const int t = blockIdx.x * 256 + threadIdx.x;
  const int s = t >> 8;
  const int bh = (t >> 3) & 31;
  const int d8 = (t & 7) * 8;
  const float* src = Kg + (size_t)s * ROWSTRIDE + bh * HDIM + d8;
  const float4 a = *(const float4*)src;
  const float4 b = *(const float4*)(src + 4);
  bf16x8 o = {(__bf16)a.x, (__bf16)a.y, (__bf16)a.z, (__bf16)a.w,
              (__bf16)b.x, (__bf16)b.y, (__bf16)b.z, (__bf16)b.w};
  *(bf16x8*)(Kb + ((size_t)bh * SEQ + s) * HDIM + d8) = o;
}

// ---- pre-pass 2: V fp32 [s][b][h][d] -> bf16 transposed [bh][d][s] ----
__global__ __launch_bounds__(256)
void conv_v(const float* __restrict__ Vg, __bf16* __restrict__ Vt) {
  __shared__ __bf16 tt[HDIM][72];
  const int s0 = blockIdx.x * 64;
  const int bh = blockIdx.y;
  const int tid = threadIdx.x;
  {
    const int r = tid >> 2, c16 = (tid & 3) * 16;
#pragma unroll
    for (int i = 0; i < 4; ++i) {
      const float4 v = *(const float4*)(Vg + (size_t)(s0 + r) * ROWSTRIDE +
                                        bh * HDIM + c16 + 4 * i);
      tt[c16 + 4 * i + 0][r] = (__bf16)v.x;
      tt[c16 + 4 * i + 1][r] = (__bf16)v.y;
      tt[c16 + 4 * i + 2][r] = (__bf16)v.z;
      tt[c16 + 4 * i + 3][r] = (__bf16)v.w;
    }
  }
  __syncthreads();
  {
    const int d = tid >> 2, s4 = (tid & 3) * 16;
    const bf16x8 o0 = *(const bf16x8*)&tt[d][s4];
    const bf16x8 o1 = *(const bf16x8*)&tt[d][s4 + 8];
    __bf16* dst = Vt + ((size_t)bh * HDIM + d) * SEQ + s0 + s4;
    *(bf16x8*)dst = o0;
    *(bf16x8*)(dst + 8) = o1;
  }
}

// ---- main: no K/V staging, no main-loop barriers ----
__global__ __launch_bounds__(256, 3)
void ntk_attn(const float* __restrict__ Qg, const __bf16* __restrict__ Kb,
              const __bf16* __restrict__ Vt, const float* __restrict__ PKg,
              const float* __restrict__ PKVg, float* __restrict__ Og) {
  __shared__ __bf16 Zts[HDIM * ZSTR];
  __shared__ __bf16 Ps[4][16 * PSTR];
  __shared__ float kks[HDIM];
  __shared__ float red[4][16];

  const int tid = threadIdx.x;
  const int w = tid >> 6, l = tid & 63, lr = l & 15, lg = l >> 4;
  const int bh = blockIdx.y, h = bh & (NHEAD - 1);
  const int bx = NQT - 1 - blockIdx.x;    // longest blocks dispatch first
  const int q0 = bx * QBLK;
  const int headoff = bh * HDIM;
  const __bf16* Kbh = Kb + (size_t)bh * SEQ * HDIM;
  const __bf16* Vbh = Vt + (size_t)bh * HDIM * SEQ;

  // ---- Q fragments (pre-scaled by 1/sqrt(d)) + phi(Q); m'=0 softmax ref ----
  bf16x8 aq[2], pq[2];
  {
    const float* qp = Qg + (size_t)(q0 + w * 16 + lr) * ROWSTRIDE + headoff + lg * 8;
#pragma unroll
    for (int c = 0; c < 2; ++c) {
      const float4 x0 = *(const float4*)(qp + 32 * c);
      const float4 x1 = *(const float4*)(qp + 32 * c + 4);
      const float f[8] = {x0.x, x0.y, x0.z, x0.w, x1.x, x1.y, x1.z, x1.w};
#pragma unroll
      for (int i = 0; i < 8; ++i) {
        aq[c][i] = (__bf16)(f[i] * 0.125f);
        const float xs = f[i] * 0.3535533905932738f;
        pq[c][i] = (__bf16)(xs > 0.f ? xs + 1.f : __expf(xs));
      }
    }
  }

  // ---- stage Zt (transposed, swizzled) and |kk|; the ONLY barrier ----
  {
#pragma unroll
    for (int it = 0; it < 4; ++it) {
      const int din = (tid >> 4) + 16 * it;
      const int c4 = (tid & 15) * 4;
      const float4 z = *(const float4*)(PKVg + (size_t)h * HDIM * HDIM +
                                        (size_t)din * HDIM + c4);
      Zts[zswz(c4 + 0, din)] = (__bf16)z.x;
      Zts[zswz(c4 + 1, din)] = (__bf16)z.y;
      Zts[zswz(c4 + 2, din)] = (__bf16)z.z;
      Zts[zswz(c4 + 3, din)] = (__bf16)z.w;
    }
    if (tid < HDIM) kks[tid] = fabsf(PKg[h * HDIM + tid]);
  }
  __syncthreads();

  const f32x4 z4 = {0.f, 0.f, 0.f, 0.f};
  f32x4 oacc[4] = {z4, z4, z4, z4};
  float lsum[4] = {0.f, 0.f, 0.f, 0.f};
  const int qrb = q0 + w * 16 + lg * 4;

  // ---- direct global fragment loads (16B/lane, L1/L2-resident) ----
  auto loadK = [&](int kb, bf16x8 kc[4][2]) {
#pragma unroll
    for (int nj = 0; nj < 4; ++nj)
#pragma unroll
      for (int c = 0; c < 2; ++c)
        kc[nj][c] = *(const bf16x8*)(Kbh + (size_t)(kb * KVBLK + nj * 16 + lr) * HDIM +
                                     32 * c + 8 * lg);
  };
  auto loadV = [&](int kb, bf16x8 vc[2][4]) {
#pragma unroll
    for (int c = 0; c < 2; ++c)
#pragma unroll
      for (int dj = 0; dj < 4; ++dj)
        vc[c][dj] = *(const bf16x8*)(Vbh + (size_t)(dj * 16 + lr) * SEQ +
                                     kb * KVBLK + 32 * c + 8 * lg);
  };

  auto TILE = [&](const bf16x8 kc[4][2], const bf16x8 vc[2][4], int kb) {
    // S = (Q/sqrt(d)) K^T
    float sv[4][4];
    __builtin_amdgcn_s_setprio(1);
#pragma unroll
    for (int nj = 0; nj < 4; ++nj) {
      f32x4 acc = z4;
#pragma unroll
      for (int c = 0; c < 2; ++c)
        acc = __builtin_amdgcn_mfma_f32_16x16x32_bf16(aq[c], kc[nj][c], acc, 0, 0, 0);
#pragma unroll
      for (int r = 0; r < 4; ++r) sv[nj][r] = acc[r];
    }
    __builtin_amdgcn_s_setprio(0);

    // P = exp(S) (mask only the diagonal tile) -> per-wave LDS
    const int kv0 = kb * KVBLK;
    if (kb == bx) {
#pragma unroll
      for (int nj = 0; nj < 4; ++nj) {
        const int col = kv0 + nj * 16 + lr;
#pragma unroll
        for (int r = 0; r < 4; ++r) {
          const float p = (col <= qrb + r) ? __expf(sv[nj][r]) : 0.f;
          lsum[r] += p;
          Ps[w][(lg * 4 + r) * PSTR + nj * 16 + lr] = (__bf16)p;
        }
      }
    } else {
#pragma unroll
      for (int nj = 0; nj < 4; ++nj)
#pragma unroll
        for (int r = 0; r < 4; ++r) {
          const float p = __expf(sv[nj][r]);
          lsum[r] += p;
          Ps[w][(lg * 4 + r) * PSTR + nj * 16 + lr] = (__bf16)p;
        }
    }
    asm volatile("s_waitcnt lgkmcnt(0)" ::: "memory");
    __builtin_amdgcn_sched_barrier(0);

    // O += P V
    __builtin_amdgcn_s_setprio(1);
#pragma unroll
    for (int c = 0; c < 2; ++c) {
      const bf16x8 ap = *(const bf16x8*)&Ps[w][lr * PSTR + 32 * c + lg * 8];
#pragma unroll
      for (int dj = 0; dj < 4; ++dj)
        oacc[dj] = __builtin_amdgcn_mfma_f32_16x16x32_bf16(ap, vc[c][dj], oacc[dj], 0, 0, 0);
    }
    __builtin_amdgcn_s_setprio(0);
  };

  // ---- main loop: K ping-pong prefetch, V issued at tile start ----
  bf16x8 kA[4][2], kB[4][2], vc[2][4];
  loadK(0, kA);
  int kb = 0;
  while (true) {
    if (kb > bx) break;
    loadV(kb, vc);
    if (kb < bx) loadK(kb + 1, kB);
    TILE(kA, vc, kb);
    ++kb;
    if (kb > bx) break;
    loadV(kb, vc);
    if (kb < bx) loadK(kb + 1, kA);
    TILE(kB, vc, kb);
    ++kb;
  }

  // ---- phi_q . kk, broadcast via per-wave LDS ----
  float pkk = 0.f;
#pragma unroll
  for (int c = 0; c < 2; ++c)
#pragma unroll
    for (int i = 0; i < 8; ++i)
      pkk += (float)pq[c][i] * kks[32 * c + lg * 8 + i];
  pkk += __shfl_xor(pkk, 16);
  pkk += __shfl_xor(pkk, 32);
  if (l < 16) red[w][l] = pkk;
  asm volatile("s_waitcnt lgkmcnt(0)" ::: "memory");
  __builtin_amdgcn_sched_barrier(0);

  // ---- epilogue: phi_q @ Z (MFMA), normalize, write ----
  f32x4 zacc[4] = {z4, z4, z4, z4};
  __builtin_amdgcn_s_setprio(1);
#pragma unroll
  for (int c = 0; c < 2; ++c) {
#pragma unroll
    for (int dj = 0; dj < 4; ++dj) {
      const bf16x8 bz = *(const bf16x8*)&Zts[zswz(dj * 16 + lr, 32 * c + lg * 8)];
      zacc[dj] = __builtin_amdgcn_mfma_f32_16x16x32_bf16(pq[c], bz, zacc[dj], 0, 0, 0);
    }
  }
  __builtin_amdgcn_s_setprio(0);

#pragma unroll
  for (int r = 0; r < 4; ++r) {
    float s = lsum[r];
    s += __shfl_xor(s, 1); s += __shfl_xor(s, 2);
    s += __shfl_xor(s, 4); s += __shfl_xor(s, 8);
    const float rd = 1.f / (s + red[w][lg * 4 + r]);
    float* op = Og + (size_t)(q0 + w * 16 + lg * 4 + r) * ROWSTRIDE + headoff;
#pragma unroll
    for (int dj = 0; dj < 4; ++dj)
      op[dj * 16 + lr] = (oacc[dj][r] + zacc[dj][r]) * rd;
  }
}

extern "C" void kernel_launch(void* const* d_in, const int* in_sizes, int n_in,
                              void* d_out, int out_size, void* d_ws, size_t ws_size,
                              hipStream_t stream) {
  const float* Qg  = (const float*)d_in[0];
  const float* Kg  = (const float*)d_in[1];
  const float* Vg  = (const float*)d_in[2];
  const float* PKg  = (const float*)d_in[4];
  const float* PKVg = (const float*)d_in[5];
  float* Og = (float*)d_out;

  __bf16* Kb = (__bf16*)d_ws;                       // [bh][s][d]  8 MB
  __bf16* Vt = Kb + (size_t)NBH * SEQ * HDIM;       // [bh][d][s]  8 MB

  conv_k<<<dim3(SEQ * NBH * 8 / 256), dim3(256), 0, stream>>>(Kg, Kb);
  conv_v<<<dim3(SEQ / 64, NBH), dim3(256), 0, stream>>>(Vg, Vt);
  ntk_attn<<<dim3(NQT, NBH), dim3(256), 0, stream>>>(Qg, Kb, Vt, PKg, PKVg, Og);
}

// Round 10
// 89.249 us; speedup vs baseline: 2.7432x; 2.7432x over previous
//
#include <hip/hip_runtime.h>

#define SEQ 2048
#define BSZ 2
#define NHEAD 16
#define NBH (BSZ * NHEAD)   // 32
#define HDIM 64
#define QBLK 128
#define KVBLK 64
#define NQT (SEQ / QBLK)    // 16
#define KSTR 88             // K tile LDS stride (bf16 elems)
#define SSTR 88             // Vt tile LDS stride
#define ZSTR 72             // Zt LDS stride
#define ROWSTRIDE (BSZ * NHEAD * HDIM)

typedef __bf16 bf16x8 __attribute__((ext_vector_type(8)));
typedef __bf16 bf16x4 __attribute__((ext_vector_type(4)));
typedef float f32x4 __attribute__((ext_vector_type(4)));

__device__ __forceinline__ int zswz(int row, int col) {
  return row * ZSTR + (col ^ (((row >> 2) & 7) << 3));
}

// ---- pre-pass 1: K fp32 [s][b][h][d] -> bf16 [bh][s][d] ----
__global__ __launch_bounds__(256)
void conv_k(const float* __restrict__ Kg, __bf16* __restrict__ Kb) {
  const int t = blockIdx.x * 256 + threadIdx.x;
  const int s = t >> 8;
  const int bh = (t >> 3) & 31;
  const int d8 = (t & 7) * 8;
  const float* src = Kg + (size_t)s * ROWSTRIDE + bh * HDIM + d8;
  const float4 a = *(const float4*)src;
  const float4 b = *(const float4*)(src + 4);
  bf16x8 o = {(__bf16)a.x, (__bf16)a.y, (__bf16)a.z, (__bf16)a.w,
              (__bf16)b.x, (__bf16)b.y, (__bf16)b.z, (__bf16)b.w};
  *(bf16x8*)(Kb + ((size_t)bh * SEQ + s) * HDIM + d8) = o;
}

// ---- pre-pass 2: V fp32 [s][b][h][d] -> bf16 transposed [bh][d][s] ----
__global__ __launch_bounds__(256)
void conv_v(const float* __restrict__ Vg, __bf16* __restrict__ Vt) {
  __shared__ __bf16 tt[HDIM][72];
  const int s0 = blockIdx.x * 64;
  const int bh = blockIdx.y;
  const int tid = threadIdx.x;
  {
    const int r = tid >> 2, c16 = (tid & 3) * 16;
#pragma unroll
    for (int i = 0; i < 4; ++i) {
      const float4 v = *(const float4*)(Vg + (size_t)(s0 + r) * ROWSTRIDE +
                                        bh * HDIM + c16 + 4 * i);
      tt[c16 + 4 * i + 0][r] = (__bf16)v.x;
      tt[c16 + 4 * i + 1][r] = (__bf16)v.y;
      tt[c16 + 4 * i + 2][r] = (__bf16)v.z;
      tt[c16 + 4 * i + 3][r] = (__bf16)v.w;
    }
  }
  __syncthreads();
  {
    const int d = tid >> 2, s4 = (tid & 3) * 16;
    const bf16x8 o0 = *(const bf16x8*)&tt[d][s4];
    const bf16x8 o1 = *(const bf16x8*)&tt[d][s4 + 8];
    __bf16* dst = Vt + ((size_t)bh * HDIM + d) * SEQ + s0 + s4;
    *(bf16x8*)dst = o0;
    *(bf16x8*)(dst + 8) = o1;
  }
}

// ---- main: swapped QK^T, P in registers via k-permuted PV, vector staging ----
__global__ __launch_bounds__(256, 3)
void ntk_attn(const float* __restrict__ Qg, const __bf16* __restrict__ Kb,
              const __bf16* __restrict__ Vt, const float* __restrict__ PKg,
              const float* __restrict__ PKVg, float* __restrict__ Og) {
  __shared__ __bf16 Ks[KVBLK * KSTR];    // K tile [kv][d]
  __shared__ __bf16 Vts[HDIM * SSTR];    // V^T tile [d][kv]
  __shared__ __bf16 Zts[HDIM * ZSTR];    // Z transposed, swizzled
  __shared__ float kks[HDIM];
  __shared__ float red[4][2][16];

  const int tid = threadIdx.x;
  const int w = tid >> 6, l = tid & 63, lr = l & 15, lg = l >> 4;
  const int bh = blockIdx.y, h = bh & (NHEAD - 1);
  const int bx = NQT - 1 - blockIdx.x;   // longest blocks dispatch first
  const int q0 = bx * QBLK;
  const int headoff = bh * HDIM;
  const int ntile = 2 * bx + 2;          // KV tiles 0..2bx+1
  const __bf16* Kbh = Kb + (size_t)bh * SEQ * HDIM;
  const __bf16* Vbh = Vt + (size_t)bh * HDIM * SEQ;

  // ---- Q fragments (pre-scaled by 1/sqrt(d)) + phi(Q), 2 groups; m'=0 ----
  bf16x8 aq[2][2], pq[2][2];
#pragma unroll
  for (int g = 0; g < 2; ++g) {
    const float* qp = Qg + (size_t)(q0 + 64 * g + w * 16 + lr) * ROWSTRIDE +
                      headoff + lg * 8;
#pragma unroll
    for (int c = 0; c < 2; ++c) {
      const float4 x0 = *(const float4*)(qp + 32 * c);
      const float4 x1 = *(const float4*)(qp + 32 * c + 4);
      const float f[8] = {x0.x, x0.y, x0.z, x0.w, x1.x, x1.y, x1.z, x1.w};
#pragma unroll
      for (int i = 0; i < 8; ++i) {
        aq[g][c][i] = (__bf16)(f[i] * 0.125f);
        const float xs = f[i] * 0.3535533905932738f;
        pq[g][c][i] = (__bf16)(xs > 0.f ? xs + 1.f : __expf(xs));
      }
    }
  }

  // ---- stage Zt (transposed, swizzled) and |kk| ----
  {
#pragma unroll
    for (int it = 0; it < 4; ++it) {
      const int din = (tid >> 4) + 16 * it;
      const int c4 = (tid & 15) * 4;
      const float4 z = *(const float4*)(PKVg + (size_t)h * HDIM * HDIM +
                                        (size_t)din * HDIM + c4);
      Zts[zswz(c4 + 0, din)] = (__bf16)z.x;
      Zts[zswz(c4 + 1, din)] = (__bf16)z.y;
      Zts[zswz(c4 + 2, din)] = (__bf16)z.z;
      Zts[zswz(c4 + 3, din)] = (__bf16)z.w;
    }
    if (tid < HDIM) kks[tid] = fabsf(PKg[h * HDIM + tid]);
  }

  const f32x4 z4 = {0.f, 0.f, 0.f, 0.f};
  f32x4 oacc[2][4] = {{z4, z4, z4, z4}, {z4, z4, z4, z4}};
  float lsum[2] = {0.f, 0.f};            // per-lane, q = lr
  int qa[2];
  qa[0] = q0 + w * 16 + lr;
  qa[1] = q0 + 64 + w * 16 + lr;

  // ---- staging: bf16 coalesced loads -> vector b128 LDS writes ----
  const int stg_r = tid >> 2;            // 0..63
  const int stg_c = (tid & 3) * 16;      // 0..48
  bf16x8 kpre[2], vpre[2];
  auto issue_kv = [&](int kb) {
    const __bf16* kp = Kbh + (size_t)(kb * KVBLK + stg_r) * HDIM + stg_c;
    kpre[0] = *(const bf16x8*)kp;
    kpre[1] = *(const bf16x8*)(kp + 8);
    const __bf16* vp = Vbh + (size_t)stg_r * SEQ + kb * KVBLK + stg_c;
    vpre[0] = *(const bf16x8*)vp;
    vpre[1] = *(const bf16x8*)(vp + 8);
  };
  auto write_kv = [&]() {
    *(bf16x8*)&Ks[stg_r * KSTR + stg_c] = kpre[0];
    *(bf16x8*)&Ks[stg_r * KSTR + stg_c + 8] = kpre[1];
    *(bf16x8*)&Vts[stg_r * SSTR + stg_c] = vpre[0];
    *(bf16x8*)&Vts[stg_r * SSTR + stg_c + 8] = vpre[1];
  };

  // ---- prologue: tile 0 resident, tile 1 in flight ----
  issue_kv(0);
  write_kv();
  issue_kv(1);
  __syncthreads();

  // ==== main loop ====
  for (int kb = 0; kb < ntile; ++kb) {
    const int kv0 = kb * KVBLK;
    const bool g0act = (kb <= 2 * bx);

    // V^T fragments, shared by both groups: vv[P][dj][half] = V^T row
    // (16dj+lr), cols 16*(2P+half)+4lg .. +3  (k-permutation halves)
    bf16x4 vv[2][4][2];
#pragma unroll
    for (int P = 0; P < 2; ++P)
#pragma unroll
      for (int dj = 0; dj < 4; ++dj)
#pragma unroll
        for (int hh = 0; hh < 2; ++hh)
          vv[P][dj][hh] = *(const bf16x4*)&Vts[(dj * 16 + lr) * SSTR +
                                               (2 * P + hh) * 16 + 4 * lg];

#pragma unroll
    for (int g = 0; g < 2; ++g) {
      if (g == 0 && !g0act) continue;

      // S^T = K (Q/sqrt(d))^T : lane holds S[q=lr][k=kv0+16nj+4lg+r]
      f32x4 s4[4];
      __builtin_amdgcn_s_setprio(1);
#pragma unroll
      for (int nj = 0; nj < 4; ++nj) {
        f32x4 acc = z4;
#pragma unroll
        for (int c = 0; c < 2; ++c) {
          const bf16x8 bk = *(const bf16x8*)&Ks[(nj * 16 + lr) * KSTR +
                                                32 * c + 8 * lg];
          acc = __builtin_amdgcn_mfma_f32_16x16x32_bf16(bk, aq[g][c], acc, 0, 0, 0);
        }
        s4[nj] = acc;
      }
      __builtin_amdgcn_s_setprio(0);

      // P = exp(S) (mask only this group's diagonal tile), stays in regs
      bf16x4 p4[4];
      const bool diag = (kb == 2 * bx + g);
#pragma unroll
      for (int nj = 0; nj < 4; ++nj) {
#pragma unroll
        for (int r = 0; r < 4; ++r) {
          float e;
          if (diag) {
            const int kabs = kv0 + 16 * nj + 4 * lg + r;
            e = (kabs <= qa[g]) ? __expf(s4[nj][r]) : 0.f;
          } else {
            e = __expf(s4[nj][r]);
          }
          lsum[g] += e;
          p4[nj][r] = (__bf16)e;
        }
      }

      // O += P V via k-permuted k32 MFMAs: pair (a,b)=(2P,2P+1),
      // sigma(8lg+i) = 16a+4lg+i (i<4), 16b+4lg+(i-4) (i>=4); A and B both
      // use sigma, so the contraction is exact.
      __builtin_amdgcn_s_setprio(1);
#pragma unroll
      for (int P = 0; P < 2; ++P) {
        const bf16x8 pa = __builtin_shufflevector(p4[2 * P], p4[2 * P + 1],
                                                  0, 1, 2, 3, 4, 5, 6, 7);
#pragma unroll
        for (int dj = 0; dj < 4; ++dj) {
          const bf16x8 bv = __builtin_shufflevector(vv[P][dj][0], vv[P][dj][1],
                                                    0, 1, 2, 3, 4, 5, 6, 7);
          oacc[g][dj] = __builtin_amdgcn_mfma_f32_16x16x32_bf16(pa, bv,
                                                                oacc[g][dj], 0, 0, 0);
        }
      }
      __builtin_amdgcn_s_setprio(0);
    }

    // stage next tile (write kb+1 from regs, issue kb+2)
    if (kb < ntile - 1) {
      __syncthreads();
      write_kv();
      if (kb + 2 < ntile) issue_kv(kb + 2);
      __syncthreads();
    }
  }

  // ---- denominators per group: rowsum(q=lr) + phi_q.kk(q=lr) ----
#pragma unroll
  for (int g = 0; g < 2; ++g) {
    float pkk = 0.f;
#pragma unroll
    for (int c = 0; c < 2; ++c)
#pragma unroll
      for (int i = 0; i < 8; ++i)
        pkk += (float)pq[g][c][i] * kks[32 * c + lg * 8 + i];
    pkk += __shfl_xor(pkk, 16);
    pkk += __shfl_xor(pkk, 32);
    float s = lsum[g];
    s += __shfl_xor(s, 16);
    s += __shfl_xor(s, 32);
    const float denom = s + pkk;        // valid for q = lr
    if (l < 16) red[w][g][l] = denom;
  }
  asm volatile("s_waitcnt lgkmcnt(0)" ::: "memory");
  __builtin_amdgcn_sched_barrier(0);

  // ---- epilogue per group: phi_q @ Z (MFMA), normalize, write ----
#pragma unroll
  for (int g = 0; g < 2; ++g) {
    f32x4 zacc[4] = {z4, z4, z4, z4};
    __builtin_amdgcn_s_setprio(1);
#pragma unroll
    for (int c = 0; c < 2; ++c) {
#pragma unroll
      for (int dj = 0; dj < 4; ++dj) {
        const bf16x8 bz = *(const bf16x8*)&Zts[zswz(dj * 16 + lr, 32 * c + lg * 8)];
        zacc[dj] = __builtin_amdgcn_mfma_f32_16x16x32_bf16(pq[g][c], bz, zacc[dj], 0, 0, 0);
      }
    }
    __builtin_amdgcn_s_setprio(0);
#pragma unroll
    for (int r = 0; r < 4; ++r) {
      const float rd = 1.f / red[w][g][lg * 4 + r];
      float* op = Og + (size_t)(q0 + 64 * g + w * 16 + lg * 4 + r) * ROWSTRIDE + headoff;
#pragma unroll
      for (int dj = 0; dj < 4; ++dj)
        op[dj * 16 + lr] = (oacc[g][dj][r] + zacc[dj][r]) * rd;
    }
  }
}

extern "C" void kernel_launch(void* const* d_in, const int* in_sizes, int n_in,
                              void* d_out, int out_size, void* d_ws, size_t ws_size,
                              hipStream_t stream) {
  const float* Qg  = (const float*)d_in[0];
  const float* Kg  = (const float*)d_in[1];
  const float* Vg  = (const float*)d_in[2];
  const float* PKg  = (const float*)d_in[4];
  const float* PKVg = (const float*)d_in[5];
  float* Og = (float*)d_out;

  __bf16* Kb = (__bf16*)d_ws;                       // [bh][s][d]  8 MB
  __bf16* Vt = Kb + (size_t)NBH * SEQ * HDIM;       // [bh][d][s]  8 MB

  conv_k<<<dim3(SEQ * NBH * 8 / 256), dim3(256), 0, stream>>>(Kg, Kb);
  conv_v<<<dim3(SEQ / 64, NBH), dim3(256), 0, stream>>>(Vg, Vt);
  ntk_attn<<<dim3(NQT, NBH), dim3(256), 0, stream>>>(Qg, Kb, Vt, PKg, PKVg, Og);
}

// Round 11
// 87.237 us; speedup vs baseline: 2.8064x; 1.0231x over previous
//
#include <hip/hip_runtime.h>

#define SEQ 2048
#define BSZ 2
#define NHEAD 16
#define NBH (BSZ * NHEAD)   // 32
#define HDIM 64
#define QBLK 128
#define KVBLK 64
#define NQT (SEQ / QBLK)    // 16
#define KSTR 88             // K tile LDS stride (bf16 elems)
#define SSTR 88             // Vt tile LDS stride
#define ZSTR 72             // Zt LDS stride
#define ROWSTRIDE (BSZ * NHEAD * HDIM)

typedef __bf16 bf16x8 __attribute__((ext_vector_type(8)));
typedef __bf16 bf16x4 __attribute__((ext_vector_type(4)));
typedef float f32x4 __attribute__((ext_vector_type(4)));

__device__ __forceinline__ int zswz(int row, int col) {
  return row * ZSTR + (col ^ (((row >> 2) & 7) << 3));
}

// ---- pre-pass 1: K fp32 [s][b][h][d] -> bf16 [bh][s][d] ----
__global__ __launch_bounds__(256)
void conv_k(const float* __restrict__ Kg, __bf16* __restrict__ Kb) {
  const int t = blockIdx.x * 256 + threadIdx.x;
  const int s = t >> 8;
  const int bh = (t >> 3) & 31;
  const int d8 = (t & 7) * 8;
  const float* src = Kg + (size_t)s * ROWSTRIDE + bh * HDIM + d8;
  const float4 a = *(const float4*)src;
  const float4 b = *(const float4*)(src + 4);
  bf16x8 o = {(__bf16)a.x, (__bf16)a.y, (__bf16)a.z, (__bf16)a.w,
              (__bf16)b.x, (__bf16)b.y, (__bf16)b.z, (__bf16)b.w};
  *(bf16x8*)(Kb + ((size_t)bh * SEQ + s) * HDIM + d8) = o;
}

// ---- pre-pass 2: V fp32 [s][b][h][d] -> bf16 [bh][d][s_perm] ----
// Column permutation within each 32-s block: storage position
// p = 32P + 8g + j  holds  V[s = 32P + 16*(j>=4) + 4g + (j&3)],
// so a lane (lg=g) reads its 8 sigma-ordered PV values as one b128.
__global__ __launch_bounds__(256)
void conv_v(const float* __restrict__ Vg, __bf16* __restrict__ Vt) {
  __shared__ __bf16 tt[HDIM][72];
  const int s0 = blockIdx.x * 64;
  const int bh = blockIdx.y;
  const int tid = threadIdx.x;
  {
    const int r = tid >> 2, c16 = (tid & 3) * 16;
#pragma unroll
    for (int i = 0; i < 4; ++i) {
      const float4 v = *(const float4*)(Vg + (size_t)(s0 + r) * ROWSTRIDE +
                                        bh * HDIM + c16 + 4 * i);
      tt[c16 + 4 * i + 0][r] = (__bf16)v.x;
      tt[c16 + 4 * i + 1][r] = (__bf16)v.y;
      tt[c16 + 4 * i + 2][r] = (__bf16)v.z;
      tt[c16 + 4 * i + 3][r] = (__bf16)v.w;
    }
  }
  __syncthreads();
  {
    const int d = tid >> 2, c16 = (tid & 3) * 16;
    __bf16 ov[16];
#pragma unroll
    for (int j = 0; j < 16; ++j) {
      const int p = c16 + j;
      const int P = p >> 5;
      const int g = (p >> 3) & 3;
      const int jj = p & 7;
      ov[j] = tt[d][32 * P + 16 * (jj >> 2) + 4 * g + (jj & 3)];
    }
    __bf16* dst = Vt + ((size_t)bh * HDIM + d) * SEQ + s0 + c16;
    *(bf16x8*)dst = *(const bf16x8*)&ov[0];
    *(bf16x8*)(dst + 8) = *(const bf16x8*)&ov[8];
  }
}

// ---- main: swapped QK^T, register P, hoisted shared fragments ----
__global__ __launch_bounds__(256, 3)
void ntk_attn(const float* __restrict__ Qg, const __bf16* __restrict__ Kb,
              const __bf16* __restrict__ Vt, const float* __restrict__ PKg,
              const float* __restrict__ PKVg, float* __restrict__ Og) {
  __shared__ __bf16 Ks[KVBLK * KSTR];    // K tile [kv][d]
  __shared__ __bf16 Vts[KVBLK * SSTR];   // V^T tile [d][kv_perm]
  __shared__ __bf16 Zts[HDIM * ZSTR];    // Z transposed, swizzled
  __shared__ float kks[HDIM];
  __shared__ float red[4][2][16];

  const int tid = threadIdx.x;
  const int w = tid >> 6, l = tid & 63, lr = l & 15, lg = l >> 4;
  const int bh = blockIdx.y, h = bh & (NHEAD - 1);
  const int bx = NQT - 1 - blockIdx.x;   // longest blocks dispatch first
  const int q0 = bx * QBLK;
  const int headoff = bh * HDIM;
  const int ntile = 2 * bx + 2;          // KV tiles 0..2bx+1
  const __bf16* Kbh = Kb + (size_t)bh * SEQ * HDIM;
  const __bf16* Vbh = Vt + (size_t)bh * HDIM * SEQ;

  // ---- Q fragments (pre-scaled by 1/sqrt(d)) + phi(Q), 2 groups; m'=0 ----
  bf16x8 aq[2][2], pq[2][2];
#pragma unroll
  for (int g = 0; g < 2; ++g) {
    const float* qp = Qg + (size_t)(q0 + 64 * g + w * 16 + lr) * ROWSTRIDE +
                      headoff + lg * 8;
#pragma unroll
    for (int c = 0; c < 2; ++c) {
      const float4 x0 = *(const float4*)(qp + 32 * c);
      const float4 x1 = *(const float4*)(qp + 32 * c + 4);
      const float f[8] = {x0.x, x0.y, x0.z, x0.w, x1.x, x1.y, x1.z, x1.w};
#pragma unroll
      for (int i = 0; i < 8; ++i) {
        aq[g][c][i] = (__bf16)(f[i] * 0.125f);
        const float xs = f[i] * 0.3535533905932738f;
        pq[g][c][i] = (__bf16)(xs > 0.f ? xs + 1.f : __expf(xs));
      }
    }
  }

  // ---- stage Zt (transposed, swizzled) and |kk| ----
  {
#pragma unroll
    for (int it = 0; it < 4; ++it) {
      const int din = (tid >> 4) + 16 * it;
      const int c4 = (tid & 15) * 4;
      const float4 z = *(const float4*)(PKVg + (size_t)h * HDIM * HDIM +
                                        (size_t)din * HDIM + c4);
      Zts[zswz(c4 + 0, din)] = (__bf16)z.x;
      Zts[zswz(c4 + 1, din)] = (__bf16)z.y;
      Zts[zswz(c4 + 2, din)] = (__bf16)z.z;
      Zts[zswz(c4 + 3, din)] = (__bf16)z.w;
    }
    if (tid < HDIM) kks[tid] = fabsf(PKg[h * HDIM + tid]);
  }

  const f32x4 z4 = {0.f, 0.f, 0.f, 0.f};
  f32x4 oacc[2][4] = {{z4, z4, z4, z4}, {z4, z4, z4, z4}};
  float lsum[2] = {0.f, 0.f};            // per-lane, q = lr
  int qa[2];
  qa[0] = q0 + w * 16 + lr;
  qa[1] = q0 + 64 + w * 16 + lr;

  // ---- staging: bf16 coalesced loads -> vector b128 LDS writes ----
  const int stg_r = tid >> 2;            // 0..63
  const int stg_c = (tid & 3) * 16;      // 0..48
  bf16x8 kpre[2], vpre[2];
  auto issue_kv = [&](int kb) {
    const __bf16* kp = Kbh + (size_t)(kb * KVBLK + stg_r) * HDIM + stg_c;
    kpre[0] = *(const bf16x8*)kp;
    kpre[1] = *(const bf16x8*)(kp + 8);
    const __bf16* vp = Vbh + (size_t)stg_r * SEQ + kb * KVBLK + stg_c;
    vpre[0] = *(const bf16x8*)vp;
    vpre[1] = *(const bf16x8*)(vp + 8);
  };
  auto write_kv = [&]() {
    *(bf16x8*)&Ks[stg_r * KSTR + stg_c] = kpre[0];
    *(bf16x8*)&Ks[stg_r * KSTR + stg_c + 8] = kpre[1];
    *(bf16x8*)&Vts[stg_r * SSTR + stg_c] = vpre[0];
    *(bf16x8*)&Vts[stg_r * SSTR + stg_c + 8] = vpre[1];
  };

  // ---- prologue: tile 0 resident, tile 1 in flight ----
  issue_kv(0);
  write_kv();
  issue_kv(1);
  __syncthreads();

  // ==== main loop ====
  for (int kb = 0; kb < ntile; ++kb) {
    const int kv0 = kb * KVBLK;
    const bool g0act = (kb <= 2 * bx);

    // hoisted K fragments (shared by both q-groups): 8 x ds_read_b128
    bf16x8 kc[4][2];
#pragma unroll
    for (int nj = 0; nj < 4; ++nj)
#pragma unroll
      for (int c = 0; c < 2; ++c)
        kc[nj][c] = *(const bf16x8*)&Ks[(nj * 16 + lr) * KSTR + 32 * c + 8 * lg];

    // hoisted V^T fragments (permuted layout): 8 x ds_read_b128
    bf16x8 vv[2][4];
#pragma unroll
    for (int P = 0; P < 2; ++P)
#pragma unroll
      for (int dj = 0; dj < 4; ++dj)
        vv[P][dj] = *(const bf16x8*)&Vts[(dj * 16 + lr) * SSTR + 32 * P + 8 * lg];

#pragma unroll
    for (int g = 0; g < 2; ++g) {
      if (g == 0 && !g0act) continue;

      // S^T = K (Q/sqrt(d))^T : lane holds S[q=lr][k=kv0+16nj+4lg+r]
      f32x4 s4[4];
      __builtin_amdgcn_s_setprio(1);
#pragma unroll
      for (int nj = 0; nj < 4; ++nj) {
        f32x4 acc = z4;
#pragma unroll
        for (int c = 0; c < 2; ++c)
          acc = __builtin_amdgcn_mfma_f32_16x16x32_bf16(kc[nj][c], aq[g][c], acc, 0, 0, 0);
        s4[nj] = acc;
      }
      __builtin_amdgcn_s_setprio(0);

      // P = exp(S) (mask only this group's diagonal tile), stays in regs
      bf16x4 p4[4];
      const bool diag = (kb == 2 * bx + g);
#pragma unroll
      for (int nj = 0; nj < 4; ++nj) {
#pragma unroll
        for (int r = 0; r < 4; ++r) {
          float e;
          if (diag) {
            const int kabs = kv0 + 16 * nj + 4 * lg + r;
            e = (kabs <= qa[g]) ? __expf(s4[nj][r]) : 0.f;
          } else {
            e = __expf(s4[nj][r]);
          }
          lsum[g] += e;
          p4[nj][r] = (__bf16)e;
        }
      }

      // O += P V via sigma-permuted k32 MFMAs (A and B share sigma; exact)
      __builtin_amdgcn_s_setprio(1);
#pragma unroll
      for (int P = 0; P < 2; ++P) {
        const bf16x8 pa = __builtin_shufflevector(p4[2 * P], p4[2 * P + 1],
                                                  0, 1, 2, 3, 4, 5, 6, 7);
#pragma unroll
        for (int dj = 0; dj < 4; ++dj)
          oacc[g][dj] = __builtin_amdgcn_mfma_f32_16x16x32_bf16(pa, vv[P][dj],
                                                                oacc[g][dj], 0, 0, 0);
      }
      __builtin_amdgcn_s_setprio(0);
    }

    // stage next tile (write kb+1 from regs, issue kb+2)
    if (kb < ntile - 1) {
      __syncthreads();
      write_kv();
      if (kb + 2 < ntile) issue_kv(kb + 2);
      __syncthreads();
    }
  }

  // ---- denominators per group: rowsum(q=lr) + phi_q.kk(q=lr) ----
#pragma unroll
  for (int g = 0; g < 2; ++g) {
    float pkk = 0.f;
#pragma unroll
    for (int c = 0; c < 2; ++c)
#pragma unroll
      for (int i = 0; i < 8; ++i)
        pkk += (float)pq[g][c][i] * kks[32 * c + lg * 8 + i];
    pkk += __shfl_xor(pkk, 16);
    pkk += __shfl_xor(pkk, 32);
    float s = lsum[g];
    s += __shfl_xor(s, 16);
    s += __shfl_xor(s, 32);
    const float denom = s + pkk;        // valid for q = lr
    if (l < 16) red[w][g][l] = denom;
  }
  asm volatile("s_waitcnt lgkmcnt(0)" ::: "memory");
  __builtin_amdgcn_sched_barrier(0);

  // ---- epilogue per group: phi_q @ Z (MFMA), normalize, write ----
#pragma unroll
  for (int g = 0; g < 2; ++g) {
    f32x4 zacc[4] = {z4, z4, z4, z4};
    __builtin_amdgcn_s_setprio(1);
#pragma unroll
    for (int c = 0; c < 2; ++c) {
#pragma unroll
      for (int dj = 0; dj < 4; ++dj) {
        const bf16x8 bz = *(const bf16x8*)&Zts[zswz(dj * 16 + lr, 32 * c + lg * 8)];
        zacc[dj] = __builtin_amdgcn_mfma_f32_16x16x32_bf16(pq[g][c], bz, zacc[dj], 0, 0, 0);
      }
    }
    __builtin_amdgcn_s_setprio(0);
#pragma unroll
    for (int r = 0; r < 4; ++r) {
      const float rd = 1.f / red[w][g][lg * 4 + r];
      float* op = Og + (size_t)(q0 + 64 * g + w * 16 + lg * 4 + r) * ROWSTRIDE + headoff;
#pragma unroll
      for (int dj = 0; dj < 4; ++dj)
        op[dj * 16 + lr] = (oacc[g][dj][r] + zacc[dj][r]) * rd;
    }
  }
}

extern "C" void kernel_launch(void* const* d_in, const int* in_sizes, int n_in,
                              void* d_out, int out_size, void* d_ws, size_t ws_size,
                              hipStream_t stream) {
  const float* Qg  = (const float*)d_in[0];
  const float* Kg  = (const float*)d_in[1];
  const float* Vg  = (const float*)d_in[2];
  const float* PKg  = (const float*)d_in[4];
  const float* PKVg = (const float*)d_in[5];
  float* Og = (float*)d_out;

  __bf16* Kb = (__bf16*)d_ws;                       // [bh][s][d]  8 MB
  __bf16* Vt = Kb + (size_t)NBH * SEQ * HDIM;       // [bh][d][s_perm]  8 MB

  conv_k<<<dim3(SEQ * NBH * 8 / 256), dim3(256), 0, stream>>>(Kg, Kb);
  conv_v<<<dim3(SEQ / 64, NBH), dim3(256), 0, stream>>>(Vg, Vt);
  ntk_attn<<<dim3(NQT, NBH), dim3(256), 0, stream>>>(Qg, Kb, Vt, PKg, PKVg, Og);
}

// Round 12
// 52.335 us; speedup vs baseline: 4.6780x; 1.6669x over previous
//
#include <hip/hip_runtime.h>

#define SEQ 2048
#define BSZ 2
#define NHEAD 16
#define NBH (BSZ * NHEAD)   // 32
#define HDIM 64
#define QBLK 64
#define KVBLK 64
#define NQT (SEQ / QBLK)    // 32
#define KSTR 88             // K tile LDS stride (bf16 elems)
#define SSTR 88             // Vt tile LDS stride
#define ZSTR 72             // Zt LDS stride
#define ROWSTRIDE (BSZ * NHEAD * HDIM)

typedef __bf16 bf16x8 __attribute__((ext_vector_type(8)));
typedef __bf16 bf16x4 __attribute__((ext_vector_type(4)));
typedef float f32x4 __attribute__((ext_vector_type(4)));

__device__ __forceinline__ int zswz(int row, int col) {
  return row * ZSTR + (col ^ (((row >> 2) & 7) << 3));
}

// ---- pre-pass 1: K fp32 [s][b][h][d] -> bf16 [bh][s][d] ----
__global__ __launch_bounds__(256)
void conv_k(const float* __restrict__ Kg, __bf16* __restrict__ Kb) {
  const int t = blockIdx.x * 256 + threadIdx.x;
  const int s = t >> 8;
  const int bh = (t >> 3) & 31;
  const int d8 = (t & 7) * 8;
  const float* src = Kg + (size_t)s * ROWSTRIDE + bh * HDIM + d8;
  const float4 a = *(const float4*)src;
  const float4 b = *(const float4*)(src + 4);
  bf16x8 o = {(__bf16)a.x, (__bf16)a.y, (__bf16)a.z, (__bf16)a.w,
              (__bf16)b.x, (__bf16)b.y, (__bf16)b.z, (__bf16)b.w};
  *(bf16x8*)(Kb + ((size_t)bh * SEQ + s) * HDIM + d8) = o;
}

// ---- pre-pass 2: V fp32 [s][b][h][d] -> bf16 [bh][d][s_perm] ----
// Storage position p = 32P + 8g + j holds V[s = 32P + 16*(j>=4) + 4g + (j&3)]:
// lane (lg=g) reads its 8 sigma-ordered PV values as one b128.
__global__ __launch_bounds__(256)
void conv_v(const float* __restrict__ Vg, __bf16* __restrict__ Vt) {
  __shared__ __bf16 tt[HDIM][72];
  const int s0 = blockIdx.x * 64;
  const int bh = blockIdx.y;
  const int tid = threadIdx.x;
  {
    const int r = tid >> 2, c16 = (tid & 3) * 16;
#pragma unroll
    for (int i = 0; i < 4; ++i) {
      const float4 v = *(const float4*)(Vg + (size_t)(s0 + r) * ROWSTRIDE +
                                        bh * HDIM + c16 + 4 * i);
      tt[c16 + 4 * i + 0][r] = (__bf16)v.x;
      tt[c16 + 4 * i + 1][r] = (__bf16)v.y;
      tt[c16 + 4 * i + 2][r] = (__bf16)v.z;
      tt[c16 + 4 * i + 3][r] = (__bf16)v.w;
    }
  }
  __syncthreads();
  {
    const int d = tid >> 2, c16 = (tid & 3) * 16;
    __bf16 ov[16];
#pragma unroll
    for (int j = 0; j < 16; ++j) {
      const int p = c16 + j;
      const int P = p >> 5;
      const int g = (p >> 3) & 3;
      const int jj = p & 7;
      ov[j] = tt[d][32 * P + 16 * (jj >> 2) + 4 * g + (jj & 3)];
    }
    __bf16* dst = Vt + ((size_t)bh * HDIM + d) * SEQ + s0 + c16;
    *(bf16x8*)dst = *(const bf16x8*)&ov[0];
    *(bf16x8*)(dst + 8) = *(const bf16x8*)&ov[8];
  }
}

// ---- main: QBLK=64, balanced work-swizzle, 4 blocks/CU ----
__global__ __launch_bounds__(256, 4)
void ntk_attn(const float* __restrict__ Qg, const __bf16* __restrict__ Kb,
              const __bf16* __restrict__ Vt, const float* __restrict__ PKg,
              const float* __restrict__ PKVg, float* __restrict__ Og) {
  __shared__ __bf16 Ks[KVBLK * KSTR];    // K tile [kv][d]
  __shared__ __bf16 Vts[KVBLK * SSTR];   // V^T tile [d][kv_perm]
  __shared__ __bf16 Zts[HDIM * ZSTR];    // Z transposed, swizzled
  __shared__ float kks[HDIM];
  __shared__ float red[4][16];

  const int tid = threadIdx.x;
  const int w = tid >> 6, l = tid & 63, lr = l & 15, lg = l >> 4;

  // Work swizzle: CU hosts ords {c, c+256, c+512, c+768} (round-robin) ->
  // v in {v0, v0+8, v0+16, v0+24}; bx = v<16 ? v : 47-v pairs g(v)+g(v+16)=31,
  // so each CU's 4 blocks sum to exactly 62 tiles (perfect balance heuristic).
  const int ord = blockIdx.x;
  const int bh = ord & 31, h = bh & (NHEAD - 1);
  const int v = ord >> 5;
  const int bx = (v < 16) ? v : 47 - v;
  const int q0 = bx * QBLK;
  const int ntile = bx + 1;              // kv tiles 0..bx
  const int headoff = bh * HDIM;
  const __bf16* Kbh = Kb + (size_t)bh * SEQ * HDIM;
  const __bf16* Vbh = Vt + (size_t)bh * HDIM * SEQ;

  // ---- Q fragments (pre-scaled by 1/sqrt(d)) + phi(Q); m'=0 softmax ref ----
  bf16x8 aq[2], pq[2];
  {
    const float* qp = Qg + (size_t)(q0 + w * 16 + lr) * ROWSTRIDE + headoff + lg * 8;
#pragma unroll
    for (int c = 0; c < 2; ++c) {
      const float4 x0 = *(const float4*)(qp + 32 * c);
      const float4 x1 = *(const float4*)(qp + 32 * c + 4);
      const float f[8] = {x0.x, x0.y, x0.z, x0.w, x1.x, x1.y, x1.z, x1.w};
#pragma unroll
      for (int i = 0; i < 8; ++i) {
        aq[c][i] = (__bf16)(f[i] * 0.125f);
        const float xs = f[i] * 0.3535533905932738f;
        pq[c][i] = (__bf16)(xs > 0.f ? xs + 1.f : __expf(xs));
      }
    }
  }

  // ---- stage Zt (transposed, swizzled) and |kk| ----
  {
#pragma unroll
    for (int it = 0; it < 4; ++it) {
      const int din = (tid >> 4) + 16 * it;
      const int c4 = (tid & 15) * 4;
      const float4 z = *(const float4*)(PKVg + (size_t)h * HDIM * HDIM +
                                        (size_t)din * HDIM + c4);
      Zts[zswz(c4 + 0, din)] = (__bf16)z.x;
      Zts[zswz(c4 + 1, din)] = (__bf16)z.y;
      Zts[zswz(c4 + 2, din)] = (__bf16)z.z;
      Zts[zswz(c4 + 3, din)] = (__bf16)z.w;
    }
    if (tid < HDIM) kks[tid] = fabsf(PKg[h * HDIM + tid]);
  }

  const f32x4 z4 = {0.f, 0.f, 0.f, 0.f};
  f32x4 oacc[4] = {z4, z4, z4, z4};
  float lsum = 0.f;                      // per-lane, q = lr
  const int qa = q0 + w * 16 + lr;

  // ---- staging: bf16 coalesced loads -> vector b128 LDS writes ----
  const int stg_r = tid >> 2;            // 0..63
  const int stg_c = (tid & 3) * 16;      // 0..48
  bf16x8 kpre[2], vpre[2];
  auto issue_kv = [&](int kb) {
    const __bf16* kp = Kbh + (size_t)(kb * KVBLK + stg_r) * HDIM + stg_c;
    kpre[0] = *(const bf16x8*)kp;
    kpre[1] = *(const bf16x8*)(kp + 8);
    const __bf16* vp = Vbh + (size_t)stg_r * SEQ + kb * KVBLK + stg_c;
    vpre[0] = *(const bf16x8*)vp;
    vpre[1] = *(const bf16x8*)(vp + 8);
  };
  auto write_kv = [&]() {
    *(bf16x8*)&Ks[stg_r * KSTR + stg_c] = kpre[0];
    *(bf16x8*)&Ks[stg_r * KSTR + stg_c + 8] = kpre[1];
    *(bf16x8*)&Vts[stg_r * SSTR + stg_c] = vpre[0];
    *(bf16x8*)&Vts[stg_r * SSTR + stg_c + 8] = vpre[1];
  };

  // ---- prologue: tile 0 resident, tile 1 in flight ----
  issue_kv(0);
  write_kv();
  if (ntile > 1) issue_kv(1);
  __syncthreads();

  // ==== main loop ====
  for (int kb = 0; kb < ntile; ++kb) {
    const int kv0 = kb * KVBLK;

    // K fragments: 8 x ds_read_b128
    bf16x8 kc[4][2];
#pragma unroll
    for (int nj = 0; nj < 4; ++nj)
#pragma unroll
      for (int c = 0; c < 2; ++c)
        kc[nj][c] = *(const bf16x8*)&Ks[(nj * 16 + lr) * KSTR + 32 * c + 8 * lg];

    // V^T fragments (permuted layout): 8 x ds_read_b128
    bf16x8 vv[2][4];
#pragma unroll
    for (int P = 0; P < 2; ++P)
#pragma unroll
      for (int dj = 0; dj < 4; ++dj)
        vv[P][dj] = *(const bf16x8*)&Vts[(dj * 16 + lr) * SSTR + 32 * P + 8 * lg];

    // S^T = K (Q/sqrt(d))^T : lane holds S[q=lr][k=kv0+16nj+4lg+r]
    f32x4 s4[4];
    __builtin_amdgcn_s_setprio(1);
#pragma unroll
    for (int nj = 0; nj < 4; ++nj) {
      f32x4 acc = z4;
#pragma unroll
      for (int c = 0; c < 2; ++c)
        acc = __builtin_amdgcn_mfma_f32_16x16x32_bf16(kc[nj][c], aq[c], acc, 0, 0, 0);
      s4[nj] = acc;
    }
    __builtin_amdgcn_s_setprio(0);

    // P = exp(S) (mask only the diagonal tile), stays in registers
    bf16x4 p4[4];
    const bool diag = (kb == bx);
#pragma unroll
    for (int nj = 0; nj < 4; ++nj) {
#pragma unroll
      for (int r = 0; r < 4; ++r) {
        float e;
        if (diag) {
          const int kabs = kv0 + 16 * nj + 4 * lg + r;
          e = (kabs <= qa) ? __expf(s4[nj][r]) : 0.f;
        } else {
          e = __expf(s4[nj][r]);
        }
        lsum += e;
        p4[nj][r] = (__bf16)e;
      }
    }

    // O += P V via sigma-permuted k32 MFMAs (A and B share sigma; exact)
    __builtin_amdgcn_s_setprio(1);
#pragma unroll
    for (int P = 0; P < 2; ++P) {
      const bf16x8 pa = __builtin_shufflevector(p4[2 * P], p4[2 * P + 1],
                                                0, 1, 2, 3, 4, 5, 6, 7);
#pragma unroll
      for (int dj = 0; dj < 4; ++dj)
        oacc[dj] = __builtin_amdgcn_mfma_f32_16x16x32_bf16(pa, vv[P][dj],
                                                           oacc[dj], 0, 0, 0);
    }
    __builtin_amdgcn_s_setprio(0);

    // stage next tile (write kb+1 from regs, issue kb+2)
    if (kb < ntile - 1) {
      __syncthreads();
      write_kv();
      if (kb + 2 < ntile) issue_kv(kb + 2);
      __syncthreads();
    }
  }

  // ---- denominator: rowsum(q=lr) + phi_q.kk(q=lr) ----
  {
    float pkk = 0.f;
#pragma unroll
    for (int c = 0; c < 2; ++c)
#pragma unroll
      for (int i = 0; i < 8; ++i)
        pkk += (float)pq[c][i] * kks[32 * c + lg * 8 + i];
    pkk += __shfl_xor(pkk, 16);
    pkk += __shfl_xor(pkk, 32);
    float s = lsum;
    s += __shfl_xor(s, 16);
    s += __shfl_xor(s, 32);
    if (l < 16) red[w][l] = s + pkk;     // valid for q = lr
  }
  asm volatile("s_waitcnt lgkmcnt(0)" ::: "memory");
  __builtin_amdgcn_sched_barrier(0);

  // ---- epilogue: phi_q @ Z (MFMA), normalize, write ----
  f32x4 zacc[4] = {z4, z4, z4, z4};
  __builtin_amdgcn_s_setprio(1);
#pragma unroll
  for (int c = 0; c < 2; ++c) {
#pragma unroll
    for (int dj = 0; dj < 4; ++dj) {
      const bf16x8 bz = *(const bf16x8*)&Zts[zswz(dj * 16 + lr, 32 * c + lg * 8)];
      zacc[dj] = __builtin_amdgcn_mfma_f32_16x16x32_bf16(pq[c], bz, zacc[dj], 0, 0, 0);
    }
  }
  __builtin_amdgcn_s_setprio(0);

#pragma unroll
  for (int r = 0; r < 4; ++r) {
    const float rd = 1.f / red[w][lg * 4 + r];
    float* op = Og + (size_t)(q0 + w * 16 + lg * 4 + r) * ROWSTRIDE + headoff;
#pragma unroll
    for (int dj = 0; dj < 4; ++dj)
      op[dj * 16 + lr] = (oacc[dj][r] + zacc[dj][r]) * rd;
  }
}

extern "C" void kernel_launch(void* const* d_in, const int* in_sizes, int n_in,
                              void* d_out, int out_size, void* d_ws, size_t ws_size,
                              hipStream_t stream) {
  const float* Qg  = (const float*)d_in[0];
  const float* Kg  = (const float*)d_in[1];
  const float* Vg  = (const float*)d_in[2];
  const float* PKg  = (const float*)d_in[4];
  const float* PKVg = (const float*)d_in[5];
  float* Og = (float*)d_out;

  __bf16* Kb = (__bf16*)d_ws;                       // [bh][s][d]  8 MB
  __bf16* Vt = Kb + (size_t)NBH * SEQ * HDIM;       // [bh][d][s_perm]  8 MB

  conv_k<<<dim3(SEQ * NBH * 8 / 256), dim3(256), 0, stream>>>(Kg, Kb);
  conv_v<<<dim3(SEQ / 64, NBH), dim3(256), 0, stream>>>(Vg, Vt);
  ntk_attn<<<dim3(NQT * NBH), dim3(256), 0, stream>>>(Qg, Kb, Vt, PKg, PKVg, Og);
}